// Round 2
// baseline (4308.858 us; speedup 1.0000x reference)
//
#include <hip/hip_runtime.h>

// ---------- constants ----------
#define B_   64
#define P_   196
#define ENC_ 512
#define ATT_ 256
#define DEC_ 256
#define EMB_ 256
#define V_   10000
#define T_   44
#define G4_  1024          // 4*DEC
#define XW_  768           // EMB+ENC (W_ih inner dim)
#define A1S_ 53248         // att1P per-b floats: 64 a4 * 208 p * 4

using short8 = __attribute__((ext_vector_type(8))) short;
using f32x4  = __attribute__((ext_vector_type(4))) float;
typedef _Float16 f16x2 __attribute__((ext_vector_type(2)));

__device__ __forceinline__ unsigned short f2bf(float f) {
    unsigned int u = __float_as_uint(f);
    unsigned int r = (u + 0x7fffu + ((u >> 16) & 1u)) >> 16;
    return (unsigned short)r;
}

__device__ __forceinline__ unsigned int pkh2(float a, float b) {
    f16x2 t; t.x = (_Float16)a; t.y = (_Float16)b;
    return __builtin_bit_cast(unsigned int, t);
}

// fp16x2 (bits carried in a float) * fp16x2 -> fp32 accumulate
__device__ __forceinline__ float mac2(float wbits, f16x2 xv, float acc) {
    f16x2 wv = __builtin_bit_cast(f16x2, wbits);
    acc = fmaf((float)wv.x, (float)xv.x, acc);
    acc = fmaf((float)wv.y, (float)xv.y, acc);
    return acc;
}
__device__ __forceinline__ float mac2u(unsigned int wbits, f16x2 xv, float acc) {
    f16x2 wv = __builtin_bit_cast(f16x2, wbits);
    acc = fmaf((float)wv.x, (float)xv.x, acc);
    acc = fmaf((float)wv.y, (float)xv.y, acc);
    return acc;
}

// raw barrier: drains LDS ops only; global loads stay in flight (T4)
__device__ __forceinline__ void bar() {
    asm volatile("s_waitcnt lgkmcnt(0)" ::: "memory");
    __builtin_amdgcn_s_barrier();
    asm volatile("" ::: "memory");
}

// ---------- generic 32x32 transpose: dst[k*N + n] = src[n*stride + off + k] ----------
__global__ void k_transpose(const float* __restrict__ src, float* __restrict__ dst,
                            int N, int stride, int off) {
    __shared__ float t[32][33];
    int k0 = blockIdx.x * 32, n0 = blockIdx.y * 32;
    int tx = threadIdx.x & 31, ty = threadIdx.x >> 5;
    for (int r = ty; r < 32; r += 8)
        t[r][tx] = src[(size_t)(n0 + r) * stride + off + k0 + tx];
    __syncthreads();
    for (int r = ty; r < 32; r += 8)
        dst[(size_t)(k0 + r) * N + n0 + tx] = t[tx][r];
}

// ---------- pack W_dec_att [a][d] -> WdaP4[d4*256+a] = {W[a][4d4..4d4+3]} ----------
__global__ __launch_bounds__(256) void k_packWda(const float* __restrict__ Wda,
                                                 float4* __restrict__ WdaP4) {
    int d4 = blockIdx.x, a = threadIdx.x;
    float4 v;
    v.x = Wda[(size_t)a * DEC_ + 4 * d4 + 0];
    v.y = Wda[(size_t)a * DEC_ + 4 * d4 + 1];
    v.z = Wda[(size_t)a * DEC_ + 4 * d4 + 2];
    v.w = Wda[(size_t)a * DEC_ + 4 * d4 + 3];
    WdaP4[(size_t)d4 * 256 + a] = v;
}

// ---------- pack gate weights fp16: Wg4[k2*256+d] = 4 gates x half2(k=2k2,2k2+1) ----------
// k<512 -> W_ih[:, k] (ctx part); k>=512 -> W_hh[:, k-512] (h part). grid 384 x 256.
__global__ __launch_bounds__(256) void k_packWg(const float* __restrict__ Wih,
        const float* __restrict__ Whh, float4* __restrict__ Wg4) {
    int k2 = blockIdx.x, d = threadIdx.x;
    int k = 2 * k2;
    unsigned int o[4];
#pragma unroll
    for (int g = 0; g < 4; ++g) {
        int row = g * 256 + d;
        float a0, a1;
        if (k < ENC_) {
            a0 = Wih[(size_t)row * XW_ + k];
            a1 = Wih[(size_t)row * XW_ + k + 1];
        } else {
            a0 = Whh[(size_t)row * DEC_ + k - ENC_];
            a1 = Whh[(size_t)row * DEC_ + k - ENC_ + 1];
        }
        o[g] = pkh2(a0, a1);
    }
    float4 v;
    v.x = __builtin_bit_cast(float, o[0]);
    v.y = __builtin_bit_cast(float, o[1]);
    v.z = __builtin_bit_cast(float, o[2]);
    v.w = __builtin_bit_cast(float, o[3]);
    Wg4[(size_t)k2 * 256 + d] = v;
}

// ---------- pack enc fp16: encPh[(b*49+p4)*512+e] = uint2{h2(p=4p4,4p4+1), h2(4p4+2,4p4+3)} ----------
__global__ __launch_bounds__(256) void k_packenc(const float* __restrict__ enc,
                                                 uint2* __restrict__ encPh) {
    int b = blockIdx.x;
    for (int p4 = 0; p4 < 49; ++p4) {
        for (int e = threadIdx.x; e < ENC_; e += 256) {
            float a0 = enc[((size_t)b * P_ + 4 * p4 + 0) * ENC_ + e];
            float a1 = enc[((size_t)b * P_ + 4 * p4 + 1) * ENC_ + e];
            float a2 = enc[((size_t)b * P_ + 4 * p4 + 2) * ENC_ + e];
            float a3 = enc[((size_t)b * P_ + 4 * p4 + 3) * ENC_ + e];
            uint2 v; v.x = pkh2(a0, a1); v.y = pkh2(a2, a3);
            encPh[((size_t)b * 49 + p4) * ENC_ + e] = v;
        }
    }
}

// ---------- fp32 -> bf16 convert ----------
__global__ void k_cvt(const float* __restrict__ src, unsigned short* __restrict__ dst, int n) {
    int i = blockIdx.x * 256 + threadIdx.x;
    if (i < n) dst[i] = f2bf(src[i]);
}

// ---------- h0/c0 from mean-pooled encoder ----------
__global__ __launch_bounds__(256) void k_init_state(
        const float* __restrict__ enc,
        const float* __restrict__ W_init_h, const float* __restrict__ b_init_h,
        const float* __restrict__ W_init_c, const float* __restrict__ b_init_c,
        float* __restrict__ h0, float* __restrict__ c0) {
    int b = blockIdx.x, tid = threadIdx.x;
    __shared__ float avg[ENC_];
    for (int e = tid; e < ENC_; e += 256) {
        float s = 0.f;
        const float* p = enc + (size_t)b * P_ * ENC_ + e;
        for (int i = 0; i < P_; i++) s += p[(size_t)i * ENC_];
        avg[e] = s * (1.0f / (float)P_);
    }
    __syncthreads();
    int d = tid;  // 256 threads == DEC_
    float hs = b_init_h[d], cs = b_init_c[d];
    const float* wh = W_init_h + (size_t)d * ENC_;
    const float* wc = W_init_c + (size_t)d * ENC_;
    for (int e = 0; e < ENC_; e++) { float a = avg[e]; hs += a * wh[e]; cs += a * wc[e]; }
    h0[b * DEC_ + d] = hs;
    c0[b * DEC_ + d] = cs;
}

// ---------- att1P[b][a4][p(208)][4j] = sum_e enc[b,p,e] * W_enc_att[a,e] ----------
// grid: 64 b * 4 a-tiles(64)
__global__ __launch_bounds__(256) void k_att1(
        const float* __restrict__ enc, const float* __restrict__ Wea,
        float* __restrict__ att1P) {
    int b = blockIdx.x >> 2, a0 = (blockIdx.x & 3) * 64;
    __shared__ float encT[32][257];   // [e_local][p] padded
    __shared__ float Wt[64][32];      // [a_local][e_local]
    int tid = threadIdx.x;
    int pl = tid & 63, ia = tid >> 6;
    float acc[16][4];
#pragma unroll
    for (int k = 0; k < 16; k++)
#pragma unroll
        for (int qq = 0; qq < 4; qq++) acc[k][qq] = 0.f;

    for (int e0 = 0; e0 < ENC_; e0 += 32) {
        {
            int j = tid & 31, pr = tid >> 5;
            for (int pass = 0; pass < 32; pass++) {
                int p = pr + pass * 8;
                float v = 0.f;
                if (p < P_) v = enc[((size_t)b * P_ + p) * ENC_ + e0 + j];
                encT[j][p] = v;
            }
            int r = tid >> 2, c0 = (tid & 3) * 8;
#pragma unroll
            for (int i = 0; i < 8; i++)
                Wt[r][c0 + i] = Wea[(size_t)(a0 + r) * ENC_ + e0 + c0 + i];
        }
        __syncthreads();
        for (int e = 0; e < 32; e++) {
            float e0v = encT[e][pl], e1v = encT[e][pl + 64];
            float e2v = encT[e][pl + 128], e3v = encT[e][pl + 192];
#pragma unroll
            for (int k = 0; k < 16; k++) {
                float w = Wt[ia * 16 + k][e];
                acc[k][0] += w * e0v; acc[k][1] += w * e1v;
                acc[k][2] += w * e2v; acc[k][3] += w * e3v;
            }
        }
        __syncthreads();
    }
#pragma unroll
    for (int k = 0; k < 16; k++)
#pragma unroll
        for (int qq = 0; qq < 4; qq++) {
            int p = pl + 64 * qq;
            int a = a0 + ia * 16 + k;
            if (p < P_)
                att1P[(size_t)b * A1S_ + ((size_t)(a >> 2) * 208 + p) * 4 + (a & 3)] = acc[k][qq];
        }
}

// ---------- embW[(t*64+b)][j] = b_ih[j]+b_hh[j] + sum_e emb[cap(b,t)][e]*W_ih[j][512+e] ----------
__global__ __launch_bounds__(256) void k_embW(
        const int* __restrict__ caption, const float* __restrict__ embedding,
        const float* __restrict__ WiheT, const float* __restrict__ b_ih,
        const float* __restrict__ b_hh, float* __restrict__ embW) {
    int r0 = blockIdx.x * 16, tid = threadIdx.x;
    __shared__ float embL[16][256];
    __shared__ int capL[16];
    if (tid < 16) {
        int r = r0 + tid, t = r >> 6, b = r & 63;
        capL[tid] = caption[b * T_ + t];
    }
    __syncthreads();
#pragma unroll
    for (int lr = 0; lr < 16; lr++)
        embL[lr][tid] = embedding[(size_t)capL[lr] * EMB_ + tid];
    __syncthreads();
    float base0 = b_ih[tid] + b_hh[tid];
    float base1 = b_ih[tid + 256] + b_hh[tid + 256];
    float base2 = b_ih[tid + 512] + b_hh[tid + 512];
    float base3 = b_ih[tid + 768] + b_hh[tid + 768];
    float acc[16][4];
#pragma unroll
    for (int lr = 0; lr < 16; lr++) {
        acc[lr][0] = base0; acc[lr][1] = base1; acc[lr][2] = base2; acc[lr][3] = base3;
    }
    for (int e = 0; e < EMB_; e++) {
        const float* wr = WiheT + (size_t)e * G4_ + tid;
        float w0 = wr[0], w1 = wr[256], w2 = wr[512], w3 = wr[768];
#pragma unroll
        for (int lr = 0; lr < 16; lr++) {
            float ev = embL[lr][e];
            acc[lr][0] += w0 * ev; acc[lr][1] += w1 * ev;
            acc[lr][2] += w2 * ev; acc[lr][3] += w3 * ev;
        }
    }
#pragma unroll
    for (int lr = 0; lr < 16; lr++) {
        float* o = embW + (size_t)(r0 + lr) * G4_ + tid;
        o[0] = acc[lr][0]; o[256] = acc[lr][1]; o[512] = acc[lr][2]; o[768] = acc[lr][3];
    }
}

// ---------- the sequential recurrence: one block (1024 thr) per batch element ----------
__global__ __launch_bounds__(1024) void k_recur(
        const float* __restrict__ att1P, const float4* __restrict__ WdaP4,
        const float* __restrict__ W_full, const float4* __restrict__ Wg4,
        const float* __restrict__ embW, const uint2* __restrict__ encPh,
        const float* __restrict__ h0, const float* __restrict__ c0,
        unsigned short* __restrict__ Hbf, float* __restrict__ out_alpha) {
    int b = blockIdx.x, tid = threadIdx.x;
    int q = tid >> 8;        // 0..3 k-split group
    int r = tid & 255;
    int e5 = tid & 511, ph = tid >> 9, pb = ph * 24;

    __shared__ __align__(16) float h_l[DEC_];
    __shared__ __align__(16) float att2_l[ATT_];
    __shared__ __align__(16) float wf_l[ATT_];
    __shared__ __align__(4) _Float16 xh[XW_];       // [ctx fp16(512); h fp16(256)]
    __shared__ __align__(4) _Float16 alpha_h[208];
    __shared__ float p1[4][256];
    __shared__ float p2[4][256];
    __shared__ float p3[2][512];
    __shared__ __align__(16) float4 p4s[4][256];
    __shared__ float red_l[4];

    if (tid < 256) {
        float hv = h0[b * DEC_ + tid];
        h_l[tid] = hv; xh[512 + tid] = (_Float16)hv;
        wf_l[tid] = W_full[tid];
    }
    float c = (tid < 256) ? c0[b * DEC_ + tid] : 0.f;
    __syncthreads();

    const float* att1b = att1P + (size_t)b * A1S_;
    const uint2* encb  = encPh + (size_t)b * 49 * ENC_;

    for (int t = 0; t < T_; ++t) {
        float4 wA[8], wB[8];
        // ---- P1: att2 partial over d in [q*64,(q+1)*64), thread r = a
#pragma unroll
        for (int i = 0; i < 8; i++) wA[i] = WdaP4[(size_t)(q * 16 + i) * 256 + r];
#pragma unroll
        for (int i = 0; i < 8; i++) wB[i] = WdaP4[(size_t)(q * 16 + 8 + i) * 256 + r];
        float a2 = 0.f;
#pragma unroll
        for (int i = 0; i < 8; i++) {
            float4 h4 = *reinterpret_cast<const float4*>(&h_l[4 * (q * 16 + i)]);
            a2 += wA[i].x * h4.x + wA[i].y * h4.y + wA[i].z * h4.z + wA[i].w * h4.w;
        }
#pragma unroll
        for (int i = 0; i < 8; i++) {
            float4 h4 = *reinterpret_cast<const float4*>(&h_l[4 * (q * 16 + 8 + i)]);
            a2 += wB[i].x * h4.x + wB[i].y * h4.y + wB[i].z * h4.z + wB[i].w * h4.w;
        }
        p1[q][r] = a2;
        // prefetch P2 chunk0 (att1, static addresses) before the barrier
#pragma unroll
        for (int i = 0; i < 8; i++)
            wA[i] = *reinterpret_cast<const float4*>(&att1b[((size_t)(q * 16 + i) * 208 + r) * 4]);
        bar();
        if (tid < 256) att2_l[tid] = p1[0][tid] + p1[1][tid] + p1[2][tid] + p1[3][tid];
        bar();

        // ---- P2: score partial over a in [q*64,(q+1)*64), thread r = p
#pragma unroll
        for (int i = 0; i < 8; i++)
            wB[i] = *reinterpret_cast<const float4*>(&att1b[((size_t)(q * 16 + 8 + i) * 208 + r) * 4]);
        float sp = 0.f;
#pragma unroll
        for (int i = 0; i < 8; i++) {
            int a4 = q * 16 + i;
            float4 t2 = *reinterpret_cast<const float4*>(&att2_l[4 * a4]);
            float4 w4 = *reinterpret_cast<const float4*>(&wf_l[4 * a4]);
            sp += fmaxf(wA[i].x + t2.x, 0.f) * w4.x + fmaxf(wA[i].y + t2.y, 0.f) * w4.y +
                  fmaxf(wA[i].z + t2.z, 0.f) * w4.z + fmaxf(wA[i].w + t2.w, 0.f) * w4.w;
        }
#pragma unroll
        for (int i = 0; i < 8; i++) {
            int a4 = q * 16 + 8 + i;
            float4 t2 = *reinterpret_cast<const float4*>(&att2_l[4 * a4]);
            float4 w4 = *reinterpret_cast<const float4*>(&wf_l[4 * a4]);
            sp += fmaxf(wB[i].x + t2.x, 0.f) * w4.x + fmaxf(wB[i].y + t2.y, 0.f) * w4.y +
                  fmaxf(wB[i].z + t2.z, 0.f) * w4.z + fmaxf(wB[i].w + t2.w, 0.f) * w4.w;
        }
        p2[q][r] = sp;     // r >= 196 lanes hold garbage; masked below
        // prefetch P3 chunk0 (enc fp16)
        uint2 eA[8], eB[8], eC[8];
#pragma unroll
        for (int i = 0; i < 8; i++) eA[i] = encb[(size_t)(pb + i) * ENC_ + e5];
        bar();

        // ---- softmax (no max-subtraction; scores are O(+-15), exp safe in fp32)
        float ex = 0.f, alpha = 0.f;
        if (tid < 256) {
            float s = p2[0][tid] + p2[1][tid] + p2[2][tid] + p2[3][tid];
            ex = (tid < P_) ? __expf(s) : 0.f;
            float sm = ex;
#pragma unroll
            for (int off = 32; off; off >>= 1) sm += __shfl_xor(sm, off);
            if ((tid & 63) == 0) red_l[tid >> 6] = sm;
        }
#pragma unroll
        for (int i = 0; i < 8; i++) eB[i] = encb[(size_t)(pb + 8 + i) * ENC_ + e5];
        bar();
        if (tid < 256) {
            float sm = red_l[0] + red_l[1] + red_l[2] + red_l[3];
            alpha = ex / sm;
            if (tid < 208) alpha_h[tid] = (_Float16)((tid < P_) ? alpha : 0.f);
            if (tid < P_) out_alpha[(size_t)b * (T_ * P_) + t * P_ + tid] = alpha;
        }
#pragma unroll
        for (int i = 0; i < 8; i++) eC[i] = encb[(size_t)(pb + 16 + i) * ENC_ + e5];
        uint2 eX = encb[(size_t)48 * ENC_ + e5];   // p4=48 tail (consumed by ph==0 only)
        bar();

        // ---- P3: ctx partial, p4 in [pb, pb+24) (+48 for ph0), thread e = e5
        float cx = 0.f;
#pragma unroll
        for (int i = 0; i < 8; i++) {
            int p4 = pb + i;
            f16x2 a01 = *reinterpret_cast<const f16x2*>(&alpha_h[4 * p4]);
            f16x2 a23 = *reinterpret_cast<const f16x2*>(&alpha_h[4 * p4 + 2]);
            cx = mac2u(eA[i].x, a01, cx); cx = mac2u(eA[i].y, a23, cx);
        }
#pragma unroll
        for (int i = 0; i < 8; i++) {
            int p4 = pb + 8 + i;
            f16x2 a01 = *reinterpret_cast<const f16x2*>(&alpha_h[4 * p4]);
            f16x2 a23 = *reinterpret_cast<const f16x2*>(&alpha_h[4 * p4 + 2]);
            cx = mac2u(eB[i].x, a01, cx); cx = mac2u(eB[i].y, a23, cx);
        }
#pragma unroll
        for (int i = 0; i < 8; i++) {
            int p4 = pb + 16 + i;
            f16x2 a01 = *reinterpret_cast<const f16x2*>(&alpha_h[4 * p4]);
            f16x2 a23 = *reinterpret_cast<const f16x2*>(&alpha_h[4 * p4 + 2]);
            cx = mac2u(eC[i].x, a01, cx); cx = mac2u(eC[i].y, a23, cx);
        }
        if (ph == 0) {
            f16x2 a01 = *reinterpret_cast<const f16x2*>(&alpha_h[192]);
            f16x2 a23 = *reinterpret_cast<const f16x2*>(&alpha_h[194]);
            cx = mac2u(eX.x, a01, cx); cx = mac2u(eX.y, a23, cx);
        }
        p3[ph][e5] = cx;
        // prefetch P4 chunk0 + embW row (static addresses)
        int kb = q * 96;
        float4 gA[8], gB[8];
#pragma unroll
        for (int i = 0; i < 8; i++) gA[i] = Wg4[(size_t)(kb + i) * 256 + r];
        float ew0, ew1, ew2, ew3;
        {
            const float* ew = embW + ((size_t)t * B_ + b) * G4_;
            ew0 = ew[r]; ew1 = ew[r + 256]; ew2 = ew[r + 512]; ew3 = ew[r + 768];
        }
        bar();
        if (tid < 512) xh[tid] = (_Float16)(p3[0][tid] + p3[1][tid]);
        bar();

        // ---- P4: gates, k2 in [q*96,(q+1)*96), fp16 weights, thread r = d
        float4 acc = {0.f, 0.f, 0.f, 0.f};
#define LDW(arr, cc)                                                           \
    _Pragma("unroll") for (int i = 0; i < 8; i++)                              \
        arr[i] = Wg4[(size_t)(kb + (cc) * 8 + i) * 256 + r];
#define USEW(arr, cc)                                                          \
    _Pragma("unroll") for (int i = 0; i < 8; i++) {                            \
        int k2 = kb + (cc) * 8 + i;                                            \
        f16x2 xv = *reinterpret_cast<const f16x2*>(&xh[2 * k2]);               \
        acc.x = mac2(arr[i].x, xv, acc.x);                                     \
        acc.y = mac2(arr[i].y, xv, acc.y);                                     \
        acc.z = mac2(arr[i].z, xv, acc.z);                                     \
        acc.w = mac2(arr[i].w, xv, acc.w);                                     \
    }
#pragma unroll
        for (int cc = 0; cc < 12; cc += 2) {
            LDW(gB, cc + 1)
            USEW(gA, cc)
            if (cc + 2 < 12) { LDW(gA, cc + 2) }
            USEW(gB, cc + 1)
        }
#undef LDW
#undef USEW
        p4s[q][r] = acc;
        bar();

        // ---- P5: reduce partials + LSTM pointwise (torch gate order i,f,g,o)
        if (tid < 256) {
            float4 g0 = p4s[0][tid], g1 = p4s[1][tid], g2 = p4s[2][tid], g3 = p4s[3][tid];
            float gi = g0.x + g1.x + g2.x + g3.x + ew0;
            float gf = g0.y + g1.y + g2.y + g3.y + ew1;
            float gg = g0.z + g1.z + g2.z + g3.z + ew2;
            float go = g0.w + g1.w + g2.w + g3.w + ew3;
            float i_g = 1.f / (1.f + __expf(-gi));
            float f_g = 1.f / (1.f + __expf(-gf));
            float g_g = tanhf(gg);
            float o_g = 1.f / (1.f + __expf(-go));
            c = f_g * c + i_g * g_g;
            float hn = o_g * tanhf(c);
            h_l[tid] = hn;
            xh[512 + tid] = (_Float16)hn;
            Hbf[((size_t)t * B_ + b) * DEC_ + tid] = f2bf(hn);
        }
        bar();
    }
}

// ---------- logits: C[m][n] = H[m,:] . Wout[n,:] + b_out[n], bf16 MFMA ----------
__global__ __launch_bounds__(256) void k_logits(
        const unsigned short* __restrict__ Hbf, const unsigned short* __restrict__ Woutbf,
        const float* __restrict__ b_out, float* __restrict__ out) {
    int n0 = blockIdx.x * 128, m0 = blockIdx.y * 128;
    __shared__ __align__(16) unsigned short At[128][40];
    __shared__ __align__(16) unsigned short Bt[128][40];
    int tid = threadIdx.x;
    int lane = tid & 63, w = tid >> 6;
    int wm = (w & 1) * 64, wn = (w >> 1) * 64;
    f32x4 acc[4][4];
#pragma unroll
    for (int i = 0; i < 4; i++)
#pragma unroll
        for (int j = 0; j < 4; j++) acc[i][j] = (f32x4){0.f, 0.f, 0.f, 0.f};

    for (int k0 = 0; k0 < DEC_; k0 += 32) {
#pragma unroll
        for (int l = 0; l < 2; l++) {
            int idx = l * 256 + tid;         // 0..511
            int r = idx >> 2, kc = (idx & 3) * 8;
            uint4 av = *reinterpret_cast<const uint4*>(&Hbf[(size_t)(m0 + r) * DEC_ + k0 + kc]);
            *reinterpret_cast<uint4*>(&At[r][kc]) = av;
            uint4 bv = make_uint4(0u, 0u, 0u, 0u);
            if (n0 + r < V_)
                bv = *reinterpret_cast<const uint4*>(&Woutbf[(size_t)(n0 + r) * DEC_ + k0 + kc]);
            *reinterpret_cast<uint4*>(&Bt[r][kc]) = bv;
        }
        __syncthreads();
        int qk = (lane >> 4) * 8, fr = lane & 15;
        short8 a[4], bb[4];
#pragma unroll
        for (int i = 0; i < 4; i++) {
            a[i]  = *reinterpret_cast<const short8*>(&At[wm + i * 16 + fr][qk]);
            bb[i] = *reinterpret_cast<const short8*>(&Bt[wn + i * 16 + fr][qk]);
        }
#pragma unroll
        for (int i = 0; i < 4; i++)
#pragma unroll
            for (int j = 0; j < 4; j++)
                acc[i][j] = __builtin_amdgcn_mfma_f32_16x16x32_bf16(a[i], bb[j], acc[i][j], 0, 0, 0);
        __syncthreads();
    }
    int col = lane & 15, qr = (lane >> 4) * 4;
#pragma unroll
    for (int j = 0; j < 4; j++) {
        int n = n0 + wn + j * 16 + col;
        if (n < V_) {
            float bo = b_out[n];
#pragma unroll
            for (int i = 0; i < 4; i++)
#pragma unroll
                for (int rr = 0; rr < 4; rr++) {
                    int m = m0 + wm + i * 16 + qr + rr;
                    int t = m >> 6, bb2 = m & 63;
                    out[(size_t)bb2 * (T_ * V_) + (size_t)t * V_ + n] = acc[i][j][rr] + bo;
                }
        }
    }
}

// ---------- launch ----------
extern "C" void kernel_launch(void* const* d_in, const int* in_sizes, int n_in,
                              void* d_out, int out_size, void* d_ws, size_t ws_size,
                              hipStream_t stream) {
    const float* enc       = (const float*)d_in[0];
    const int*   caption   = (const int*)d_in[1];
    const float* W_enc_att = (const float*)d_in[2];
    const float* W_dec_att = (const float*)d_in[3];
    const float* W_full    = (const float*)d_in[4];
    const float* embedding = (const float*)d_in[5];
    const float* W_init_h  = (const float*)d_in[6];
    const float* b_init_h  = (const float*)d_in[7];
    const float* W_init_c  = (const float*)d_in[8];
    const float* b_init_c  = (const float*)d_in[9];
    const float* W_ih      = (const float*)d_in[10];
    const float* b_ih      = (const float*)d_in[11];
    const float* W_hh      = (const float*)d_in[12];
    const float* b_hh      = (const float*)d_in[13];
    const float* W_out     = (const float*)d_in[14];
    const float* b_out     = (const float*)d_in[15];

    float* ws = (float*)d_ws;
    float* h0      = ws;                  //      16384
    float* c0      = ws + 16384;          //      16384
    float* WdaP    = ws + 32768;          //      65536  [64 d4][256 a] float4
    float* WiheT   = ws + 98304;          //     262144  [256 e][1024 j]
    float* Wg4     = ws + 360448;         //     393216  [384 k2][256 d] 4x half2
    float* embW    = ws + 753664;         //    2883584  [t*64+b][1024]
    float* att1P   = ws + 3637248;        //    3407872  [b][a4][208][4]
    float* encPh   = ws + 7045120;        //    3211264  [b][49 p4][512 e] uint2 fp16
    unsigned short* Hbf    = (unsigned short*)(ws + 10256384);   // 2816*256 bf16
    unsigned short* Woutbf = (unsigned short*)(ws + 10616832);   // 10000*256 bf16

    float* out_pred  = (float*)d_out;
    float* out_alpha = out_pred + (size_t)B_ * T_ * V_;

    k_transpose<<<dim3(8, 32), 256, 0, stream>>>(W_ih, WiheT, G4_, XW_, ENC_);
    k_packWda<<<64, 256, 0, stream>>>(W_dec_att, (float4*)WdaP);
    k_packWg<<<384, 256, 0, stream>>>(W_ih, W_hh, (float4*)Wg4);
    k_packenc<<<64, 256, 0, stream>>>(enc, (uint2*)encPh);
    k_cvt<<<10000, 256, 0, stream>>>(W_out, Woutbf, V_ * DEC_);
    k_init_state<<<B_, 256, 0, stream>>>(enc, W_init_h, b_init_h, W_init_c, b_init_c, h0, c0);
    k_att1<<<B_ * 4, 256, 0, stream>>>(enc, W_enc_att, att1P);
    k_embW<<<176, 256, 0, stream>>>(caption, embedding, WiheT, b_ih, b_hh, embW);
    k_recur<<<B_, 1024, 0, stream>>>(att1P, (const float4*)WdaP, W_full, (const float4*)Wg4,
                                     embW, (const uint2*)encPh, h0, c0, Hbf, out_alpha);
    k_logits<<<dim3(79, 22), 256, 0, stream>>>(Hbf, Woutbf, b_out, out_pred);
}

// Round 4
// 1596.556 us; speedup vs baseline: 2.6988x; 2.6988x over previous
//
#include <hip/hip_runtime.h>

// ---------- constants ----------
#define B_   64
#define P_   196
#define ENC_ 512
#define ATT_ 256
#define DEC_ 256
#define EMB_ 256
#define V_   10000
#define T_   44
#define G4_  1024          // 4*DEC
#define XW_  768           // EMB+ENC (W_ih inner dim)

using short8 = __attribute__((ext_vector_type(8))) short;
using f32x4  = __attribute__((ext_vector_type(4))) float;
typedef _Float16 f16x2 __attribute__((ext_vector_type(2)));

__device__ __forceinline__ unsigned short f2bf(float f) {
    unsigned int u = __float_as_uint(f);
    unsigned int r = (u + 0x7fffu + ((u >> 16) & 1u)) >> 16;
    return (unsigned short)r;
}

__device__ __forceinline__ unsigned int pkh2(float a, float b) {
    f16x2 t; t.x = (_Float16)a; t.y = (_Float16)b;
    return __builtin_bit_cast(unsigned int, t);
}

// fp16x2 dot with fp32 accumulate (single V_DOT2_F32_F16 where available)
__device__ __forceinline__ float fdot2f(float wbits, f16x2 xv, float acc) {
    f16x2 wv = __builtin_bit_cast(f16x2, wbits);
#if __has_builtin(__builtin_amdgcn_fdot2)
    return __builtin_amdgcn_fdot2(wv, xv, acc, false);
#else
    acc = fmaf((float)wv.x, (float)xv.x, acc);
    acc = fmaf((float)wv.y, (float)xv.y, acc);
    return acc;
#endif
}
__device__ __forceinline__ float fdot2u(unsigned int wbits, f16x2 xv, float acc) {
    f16x2 wv = __builtin_bit_cast(f16x2, wbits);
#if __has_builtin(__builtin_amdgcn_fdot2)
    return __builtin_amdgcn_fdot2(wv, xv, acc, false);
#else
    acc = fmaf((float)wv.x, (float)xv.x, acc);
    acc = fmaf((float)wv.y, (float)xv.y, acc);
    return acc;
#endif
}

// raw barrier: drains LDS ops only; global loads stay in flight (T4).
// All inter-thread communication in k_recur goes through LDS (lgkmcnt-tracked).
__device__ __forceinline__ void bar() {
    asm volatile("s_waitcnt lgkmcnt(0)" ::: "memory");
    __builtin_amdgcn_s_barrier();
    asm volatile("" ::: "memory");
}

// ---------- generic 32x32 transpose: dst[k*N + n] = src[n*stride + off + k] ----------
__global__ void k_transpose(const float* __restrict__ src, float* __restrict__ dst,
                            int N, int stride, int off) {
    __shared__ float t[32][33];
    int k0 = blockIdx.x * 32, n0 = blockIdx.y * 32;
    int tx = threadIdx.x & 31, ty = threadIdx.x >> 5;
    for (int r = ty; r < 32; r += 8)
        t[r][tx] = src[(size_t)(n0 + r) * stride + off + k0 + tx];
    __syncthreads();
    for (int r = ty; r < 32; r += 8)
        dst[(size_t)(k0 + r) * N + n0 + tx] = t[tx][r];
}

// ---------- pack W_dec_att [a][d] -> WdaP4[d4*256+a] = {W[a][4d4..4d4+3]} ----------
__global__ __launch_bounds__(256) void k_packWda(const float* __restrict__ Wda,
                                                 float4* __restrict__ WdaP4) {
    int d4 = blockIdx.x, a = threadIdx.x;
    float4 v;
    v.x = Wda[(size_t)a * DEC_ + 4 * d4 + 0];
    v.y = Wda[(size_t)a * DEC_ + 4 * d4 + 1];
    v.z = Wda[(size_t)a * DEC_ + 4 * d4 + 2];
    v.w = Wda[(size_t)a * DEC_ + 4 * d4 + 3];
    WdaP4[(size_t)d4 * 256 + a] = v;
}

// ---------- pack gate weights fp16: Wg4[k2*256+d] = 4 gates x half2(k=2k2,2k2+1) ----------
// k<512 -> W_ih[:, k] (ctx part); k>=512 -> W_hh[:, k-512] (h part). grid 384 x 256.
__global__ __launch_bounds__(256) void k_packWg(const float* __restrict__ Wih,
        const float* __restrict__ Whh, float4* __restrict__ Wg4) {
    int k2 = blockIdx.x, d = threadIdx.x;
    int k = 2 * k2;
    unsigned int o[4];
#pragma unroll
    for (int g = 0; g < 4; ++g) {
        int row = g * 256 + d;
        float a0, a1;
        if (k < ENC_) {
            a0 = Wih[(size_t)row * XW_ + k];
            a1 = Wih[(size_t)row * XW_ + k + 1];
        } else {
            a0 = Whh[(size_t)row * DEC_ + k - ENC_];
            a1 = Whh[(size_t)row * DEC_ + k - ENC_ + 1];
        }
        o[g] = pkh2(a0, a1);
    }
    float4 v;
    v.x = __builtin_bit_cast(float, o[0]);
    v.y = __builtin_bit_cast(float, o[1]);
    v.z = __builtin_bit_cast(float, o[2]);
    v.w = __builtin_bit_cast(float, o[3]);
    Wg4[(size_t)k2 * 256 + d] = v;
}

// ---------- pack enc fp16: encPh[(b*49+p4)*512+e] = uint2{h2(p=4p4,4p4+1), h2(4p4+2,4p4+3)} ----------
__global__ __launch_bounds__(256) void k_packenc(const float* __restrict__ enc,
                                                 uint2* __restrict__ encPh) {
    int b = blockIdx.x;
    for (int p4 = 0; p4 < 49; ++p4) {
        for (int e = threadIdx.x; e < ENC_; e += 256) {
            float a0 = enc[((size_t)b * P_ + 4 * p4 + 0) * ENC_ + e];
            float a1 = enc[((size_t)b * P_ + 4 * p4 + 1) * ENC_ + e];
            float a2 = enc[((size_t)b * P_ + 4 * p4 + 2) * ENC_ + e];
            float a3 = enc[((size_t)b * P_ + 4 * p4 + 3) * ENC_ + e];
            uint2 v; v.x = pkh2(a0, a1); v.y = pkh2(a2, a3);
            encPh[((size_t)b * 49 + p4) * ENC_ + e] = v;
        }
    }
}

// ---------- fp32 -> bf16 convert ----------
__global__ void k_cvt(const float* __restrict__ src, unsigned short* __restrict__ dst, int n) {
    int i = blockIdx.x * 256 + threadIdx.x;
    if (i < n) dst[i] = f2bf(src[i]);
}

// ---------- h0/c0 from mean-pooled encoder ----------
__global__ __launch_bounds__(256) void k_init_state(
        const float* __restrict__ enc,
        const float* __restrict__ W_init_h, const float* __restrict__ b_init_h,
        const float* __restrict__ W_init_c, const float* __restrict__ b_init_c,
        float* __restrict__ h0, float* __restrict__ c0) {
    int b = blockIdx.x, tid = threadIdx.x;
    __shared__ float avg[ENC_];
    for (int e = tid; e < ENC_; e += 256) {
        float s = 0.f;
        const float* p = enc + (size_t)b * P_ * ENC_ + e;
        for (int i = 0; i < P_; i++) s += p[(size_t)i * ENC_];
        avg[e] = s * (1.0f / (float)P_);
    }
    __syncthreads();
    int d = tid;  // 256 threads == DEC_
    float hs = b_init_h[d], cs = b_init_c[d];
    const float* wh = W_init_h + (size_t)d * ENC_;
    const float* wc = W_init_c + (size_t)d * ENC_;
    for (int e = 0; e < ENC_; e++) { float a = avg[e]; hs += a * wh[e]; cs += a * wc[e]; }
    h0[b * DEC_ + d] = hs;
    c0[b * DEC_ + d] = cs;
}

// ---------- att1f2[b][a2(128)][208 p] = float2{ att1[2a2][p], att1[2a2+1][p] } ----------
// grid: 64 b * 4 a-tiles(64)
__global__ __launch_bounds__(256) void k_att1(
        const float* __restrict__ enc, const float* __restrict__ Wea,
        float2* __restrict__ att1f2) {
    int b = blockIdx.x >> 2, a0 = (blockIdx.x & 3) * 64;
    __shared__ float encT[32][257];   // [e_local][p] padded
    __shared__ float Wt[64][32];      // [a_local][e_local]
    int tid = threadIdx.x;
    int pl = tid & 63, ia = tid >> 6;
    float acc[16][4];
#pragma unroll
    for (int k = 0; k < 16; k++)
#pragma unroll
        for (int qq = 0; qq < 4; qq++) acc[k][qq] = 0.f;

    for (int e0 = 0; e0 < ENC_; e0 += 32) {
        {
            int j = tid & 31, pr = tid >> 5;
            for (int pass = 0; pass < 32; pass++) {
                int p = pr + pass * 8;
                float v = 0.f;
                if (p < P_) v = enc[((size_t)b * P_ + p) * ENC_ + e0 + j];
                encT[j][p] = v;
            }
            int r = tid >> 2, c0 = (tid & 3) * 8;
#pragma unroll
            for (int i = 0; i < 8; i++)
                Wt[r][c0 + i] = Wea[(size_t)(a0 + r) * ENC_ + e0 + c0 + i];
        }
        __syncthreads();
        for (int e = 0; e < 32; e++) {
            float e0v = encT[e][pl], e1v = encT[e][pl + 64];
            float e2v = encT[e][pl + 128], e3v = encT[e][pl + 192];
#pragma unroll
            for (int k = 0; k < 16; k++) {
                float w = Wt[ia * 16 + k][e];
                acc[k][0] += w * e0v; acc[k][1] += w * e1v;
                acc[k][2] += w * e2v; acc[k][3] += w * e3v;
            }
        }
        __syncthreads();
    }
#pragma unroll
    for (int k = 0; k < 16; k += 2)
#pragma unroll
        for (int qq = 0; qq < 4; qq++) {
            int p = pl + 64 * qq;
            int a = a0 + ia * 16 + k;
            if (p < P_) {
                float2 v; v.x = acc[k][qq]; v.y = acc[k + 1][qq];
                att1f2[((size_t)b * 128 + (a >> 1)) * 208 + p] = v;
            }
        }
}

// ---------- embW[(t*64+b)][j] = b_ih[j]+b_hh[j] + sum_e emb[cap(b,t)][e]*W_ih[j][512+e] ----------
__global__ __launch_bounds__(256) void k_embW(
        const int* __restrict__ caption, const float* __restrict__ embedding,
        const float* __restrict__ WiheT, const float* __restrict__ b_ih,
        const float* __restrict__ b_hh, float* __restrict__ embW) {
    int r0 = blockIdx.x * 16, tid = threadIdx.x;
    __shared__ float embL[16][256];
    __shared__ int capL[16];
    if (tid < 16) {
        int r = r0 + tid, t = r >> 6, b = r & 63;
        capL[tid] = caption[b * T_ + t];
    }
    __syncthreads();
#pragma unroll
    for (int lr = 0; lr < 16; lr++)
        embL[lr][tid] = embedding[(size_t)capL[lr] * EMB_ + tid];
    __syncthreads();
    float base0 = b_ih[tid] + b_hh[tid];
    float base1 = b_ih[tid + 256] + b_hh[tid + 256];
    float base2 = b_ih[tid + 512] + b_hh[tid + 512];
    float base3 = b_ih[tid + 768] + b_hh[tid + 768];
    float acc[16][4];
#pragma unroll
    for (int lr = 0; lr < 16; lr++) {
        acc[lr][0] = base0; acc[lr][1] = base1; acc[lr][2] = base2; acc[lr][3] = base3;
    }
    for (int e = 0; e < EMB_; e++) {
        const float* wr = WiheT + (size_t)e * G4_ + tid;
        float w0 = wr[0], w1 = wr[256], w2 = wr[512], w3 = wr[768];
#pragma unroll
        for (int lr = 0; lr < 16; lr++) {
            float ev = embL[lr][e];
            acc[lr][0] += w0 * ev; acc[lr][1] += w1 * ev;
            acc[lr][2] += w2 * ev; acc[lr][3] += w3 * ev;
        }
    }
#pragma unroll
    for (int lr = 0; lr < 16; lr++) {
        float* o = embW + (size_t)(r0 + lr) * G4_ + tid;
        o[0] = acc[lr][0]; o[256] = acc[lr][1]; o[512] = acc[lr][2]; o[768] = acc[lr][3];
    }
}

// ---------- the sequential recurrence: one block (1024 thr = 16 waves, 4 waves/EU) per b ----------
// Simple low-register loops (R1 structure); fp16 only on P3 enc / P4 weights (R2-validated).
__global__ __launch_bounds__(1024, 4) void k_recur(
        const float2* __restrict__ att1f2, const float4* __restrict__ WdaP4,
        const float* __restrict__ W_full, const float4* __restrict__ Wg4,
        const float* __restrict__ embW, const uint2* __restrict__ encPh,
        const float* __restrict__ h0, const float* __restrict__ c0,
        unsigned short* __restrict__ Hbf, float* __restrict__ out_alpha) {
    int b = blockIdx.x, tid = threadIdx.x;
    int q = tid >> 8;        // 0..3 k-split group
    int r = tid & 255;
    int e5 = tid & 511, ph = tid >> 9;

    __shared__ __align__(16) float h_l[DEC_];
    __shared__ __align__(16) float att2_l[ATT_];
    __shared__ __align__(16) float wf_l[ATT_];
    __shared__ __align__(16) _Float16 xh[XW_];     // [ctx fp16(512); h fp16(256)]
    __shared__ __align__(8)  _Float16 alpha_h[208];
    __shared__ float p1[4][256];
    __shared__ float p2[4][256];
    __shared__ float p3[2][512];
    __shared__ __align__(16) float4 p4s[4][256];
    __shared__ float red_l[4];

    if (tid < 256) {
        float hv = h0[b * DEC_ + tid];
        h_l[tid] = hv;
        xh[512 + tid] = (_Float16)hv;
        wf_l[tid] = W_full[tid];
    }
    float c = (tid < 256) ? c0[b * DEC_ + tid] : 0.f;
    __syncthreads();

    const float2* att1b = att1f2 + (size_t)b * (128 * 208);
    const uint2*  encb  = encPh  + (size_t)b * (49 * ENC_);

    for (int t = 0; t < T_; ++t) {
        // ---- P1: att2 partial over d in [q*64,(q+1)*64), thread r = a (fp32)
        float a2 = 0.f;
#pragma unroll 4
        for (int i = 0; i < 16; i++) {
            int d4 = q * 16 + i;
            float4 w = WdaP4[(size_t)d4 * 256 + r];
            float4 h4 = *reinterpret_cast<const float4*>(&h_l[4 * d4]);
            a2 += w.x * h4.x + w.y * h4.y + w.z * h4.z + w.w * h4.w;
        }
        p1[q][r] = a2;
        bar();
        if (tid < 256) att2_l[tid] = p1[0][tid] + p1[1][tid] + p1[2][tid] + p1[3][tid];
        bar();

        // ---- P2: score partial over a-pairs in [q*32,(q+1)*32), thread r = p (fp32)
        float sp = 0.f;
#pragma unroll 4
        for (int i = 0; i < 32; i++) {
            int a2i = q * 32 + i;
            float2 w  = att1b[(size_t)a2i * 208 + r];
            float2 t2 = *reinterpret_cast<const float2*>(&att2_l[2 * a2i]);
            float2 w4 = *reinterpret_cast<const float2*>(&wf_l[2 * a2i]);
            sp += fmaxf(w.x + t2.x, 0.f) * w4.x + fmaxf(w.y + t2.y, 0.f) * w4.y;
        }
        p2[q][r] = sp;
        bar();

        // ---- softmax (no max-subtraction; fp32 exp safe for these score magnitudes)
        float ex = 0.f;
        if (tid < 256) {
            float s = p2[0][tid] + p2[1][tid] + p2[2][tid] + p2[3][tid];
            ex = (tid < P_) ? __expf(s) : 0.f;
            float sm = ex;
#pragma unroll
            for (int off = 32; off; off >>= 1) sm += __shfl_xor(sm, off);
            if ((tid & 63) == 0) red_l[tid >> 6] = sm;
        }
        bar();
        if (tid < 256) {
            float sm = red_l[0] + red_l[1] + red_l[2] + red_l[3];
            float alpha = ex / sm;           // == 0 for tid >= P_
            if (tid < 208) alpha_h[tid] = (_Float16)alpha;
            if (tid < P_) out_alpha[(size_t)b * (T_ * P_) + t * P_ + tid] = alpha;
        }
        bar();

        // ---- P3: ctx partial, thread e = e5, p4 split 2-way (fp16 enc, fdot2)
        float cx = 0.f;
        {
            int p4b = ph ? 25 : 0, p4e = ph ? 49 : 25;
#pragma unroll 5
            for (int p4 = p4b; p4 < p4e; p4++) {
                uint2 ev = encb[(size_t)p4 * ENC_ + e5];
                f16x2 a01 = *reinterpret_cast<const f16x2*>(&alpha_h[4 * p4]);
                f16x2 a23 = *reinterpret_cast<const f16x2*>(&alpha_h[4 * p4 + 2]);
                cx = fdot2u(ev.x, a01, cx);
                cx = fdot2u(ev.y, a23, cx);
            }
        }
        p3[ph][e5] = cx;
        // embW row prefetch (used in P5; 4 VGPRs held across P4)
        float ew0 = 0.f, ew1 = 0.f, ew2 = 0.f, ew3 = 0.f;
        if (tid < 256) {
            const float* ew = embW + ((size_t)t * B_ + b) * G4_;
            ew0 = ew[tid]; ew1 = ew[tid + 256]; ew2 = ew[tid + 512]; ew3 = ew[tid + 768];
        }
        bar();
        if (tid < 512) xh[tid] = (_Float16)(p3[0][tid] + p3[1][tid]);
        bar();

        // ---- P4: gates, k2 in [q*96,(q+1)*96), fp16 weights, thread r = d (fdot2)
        float4 acc = {0.f, 0.f, 0.f, 0.f};
#pragma unroll 8
        for (int i = 0; i < 96; i++) {
            int k2 = q * 96 + i;
            float4 w = Wg4[(size_t)k2 * 256 + r];
            f16x2 xv = *reinterpret_cast<const f16x2*>(&xh[2 * k2]);
            acc.x = fdot2f(w.x, xv, acc.x);
            acc.y = fdot2f(w.y, xv, acc.y);
            acc.z = fdot2f(w.z, xv, acc.z);
            acc.w = fdot2f(w.w, xv, acc.w);
        }
        p4s[q][r] = acc;
        bar();

        // ---- P5: reduce partials + LSTM pointwise (torch gate order i,f,g,o)
        if (tid < 256) {
            float4 g0 = p4s[0][tid], g1 = p4s[1][tid], g2 = p4s[2][tid], g3 = p4s[3][tid];
            float gi = g0.x + g1.x + g2.x + g3.x + ew0;
            float gf = g0.y + g1.y + g2.y + g3.y + ew1;
            float gg = g0.z + g1.z + g2.z + g3.z + ew2;
            float go = g0.w + g1.w + g2.w + g3.w + ew3;
            float i_g = 1.f / (1.f + __expf(-gi));
            float f_g = 1.f / (1.f + __expf(-gf));
            float g_g = tanhf(gg);
            float o_g = 1.f / (1.f + __expf(-go));
            c = f_g * c + i_g * g_g;
            float hn = o_g * tanhf(c);
            h_l[tid] = hn;
            xh[512 + tid] = (_Float16)hn;
            Hbf[((size_t)t * B_ + b) * DEC_ + tid] = f2bf(hn);
        }
        bar();
    }
}

// ---------- logits: C[m][n] = H[m,:] . Wout[n,:] + b_out[n], bf16 MFMA ----------
__global__ __launch_bounds__(256) void k_logits(
        const unsigned short* __restrict__ Hbf, const unsigned short* __restrict__ Woutbf,
        const float* __restrict__ b_out, float* __restrict__ out) {
    int n0 = blockIdx.x * 128, m0 = blockIdx.y * 128;
    __shared__ __align__(16) unsigned short At[128][40];
    __shared__ __align__(16) unsigned short Bt[128][40];
    int tid = threadIdx.x;
    int lane = tid & 63, w = tid >> 6;
    int wm = (w & 1) * 64, wn = (w >> 1) * 64;
    f32x4 acc[4][4];
#pragma unroll
    for (int i = 0; i < 4; i++)
#pragma unroll
        for (int j = 0; j < 4; j++) acc[i][j] = (f32x4){0.f, 0.f, 0.f, 0.f};

    for (int k0 = 0; k0 < DEC_; k0 += 32) {
#pragma unroll
        for (int l = 0; l < 2; l++) {
            int idx = l * 256 + tid;         // 0..511
            int r = idx >> 2, kc = (idx & 3) * 8;
            uint4 av = *reinterpret_cast<const uint4*>(&Hbf[(size_t)(m0 + r) * DEC_ + k0 + kc]);
            *reinterpret_cast<uint4*>(&At[r][kc]) = av;
            uint4 bv = make_uint4(0u, 0u, 0u, 0u);
            if (n0 + r < V_)
                bv = *reinterpret_cast<const uint4*>(&Woutbf[(size_t)(n0 + r) * DEC_ + k0 + kc]);
            *reinterpret_cast<uint4*>(&Bt[r][kc]) = bv;
        }
        __syncthreads();
        int qk = (lane >> 4) * 8, fr = lane & 15;
        short8 a[4], bb[4];
#pragma unroll
        for (int i = 0; i < 4; i++) {
            a[i]  = *reinterpret_cast<const short8*>(&At[wm + i * 16 + fr][qk]);
            bb[i] = *reinterpret_cast<const short8*>(&Bt[wn + i * 16 + fr][qk]);
        }
#pragma unroll
        for (int i = 0; i < 4; i++)
#pragma unroll
            for (int j = 0; j < 4; j++)
                acc[i][j] = __builtin_amdgcn_mfma_f32_16x16x32_bf16(a[i], bb[j], acc[i][j], 0, 0, 0);
        __syncthreads();
    }
    int col = lane & 15, qr = (lane >> 4) * 4;
#pragma unroll
    for (int j = 0; j < 4; j++) {
        int n = n0 + wn + j * 16 + col;
        if (n < V_) {
            float bo = b_out[n];
#pragma unroll
            for (int i = 0; i < 4; i++)
#pragma unroll
                for (int rr = 0; rr < 4; rr++) {
                    int m = m0 + wm + i * 16 + qr + rr;
                    int t = m >> 6, bb2 = m & 63;
                    out[(size_t)bb2 * (T_ * V_) + (size_t)t * V_ + n] = acc[i][j][rr] + bo;
                }
        }
    }
}

// ---------- launch ----------
extern "C" void kernel_launch(void* const* d_in, const int* in_sizes, int n_in,
                              void* d_out, int out_size, void* d_ws, size_t ws_size,
                              hipStream_t stream) {
    const float* enc       = (const float*)d_in[0];
    const int*   caption   = (const int*)d_in[1];
    const float* W_enc_att = (const float*)d_in[2];
    const float* W_dec_att = (const float*)d_in[3];
    const float* W_full    = (const float*)d_in[4];
    const float* embedding = (const float*)d_in[5];
    const float* W_init_h  = (const float*)d_in[6];
    const float* b_init_h  = (const float*)d_in[7];
    const float* W_init_c  = (const float*)d_in[8];
    const float* b_init_c  = (const float*)d_in[9];
    const float* W_ih      = (const float*)d_in[10];
    const float* b_ih      = (const float*)d_in[11];
    const float* W_hh      = (const float*)d_in[12];
    const float* b_hh      = (const float*)d_in[13];
    const float* W_out     = (const float*)d_in[14];
    const float* b_out     = (const float*)d_in[15];

    float* ws = (float*)d_ws;
    float* h0    = ws;                    //      16384
    float* c0    = ws + 16384;            //      16384
    float* WdaP  = ws + 32768;            //      65536  [64 d4][256 a] float4
    float* WiheT = ws + 98304;            //     262144  [256 e][1024 j]
    float* Wg4   = ws + 360448;           //     393216  [384 k2][256 d] 4x half2
    float* embW  = ws + 753664;           //    2883584  [t*64+b][1024]
    float* att1  = ws + 3637248;          //    3407872  [b][128 a2][208 p] float2
    float* encPh = ws + 7045120;          //    3211264  [b][49 p4][512 e] uint2 fp16
    unsigned short* Hbf    = (unsigned short*)(ws + 10256384);   // 2816*256 bf16 = 360448 floats
    unsigned short* Woutbf = (unsigned short*)(ws + 10616832);   // 10000*256 bf16
    // total: 10616832 + 1280000 = 11896832 floats ~= 47.6 MB

    float* out_pred  = (float*)d_out;
    float* out_alpha = out_pred + (size_t)B_ * T_ * V_;

    k_transpose<<<dim3(8, 32), 256, 0, stream>>>(W_ih, WiheT, G4_, XW_, ENC_);
    k_packWda<<<64, 256, 0, stream>>>(W_dec_att, (float4*)WdaP);
    k_packWg<<<384, 256, 0, stream>>>(W_ih, W_hh, (float4*)Wg4);
    k_packenc<<<64, 256, 0, stream>>>(enc, (uint2*)encPh);
    k_cvt<<<10000, 256, 0, stream>>>(W_out, Woutbf, V_ * DEC_);
    k_init_state<<<B_, 256, 0, stream>>>(enc, W_init_h, b_init_h, W_init_c, b_init_c, h0, c0);
    k_att1<<<B_ * 4, 256, 0, stream>>>(enc, W_enc_att, (float2*)att1);
    k_embW<<<176, 256, 0, stream>>>(caption, embedding, WiheT, b_ih, b_hh, embW);
    k_recur<<<B_, 1024, 0, stream>>>((const float2*)att1, (const float4*)WdaP, W_full,
                                     (const float4*)Wg4, embW, (const uint2*)encPh,
                                     h0, c0, Hbf, out_alpha);
    k_logits<<<dim3(79, 22), 256, 0, stream>>>(Hbf, Woutbf, b_out, out_pred);
}

// Round 5
// 1414.221 us; speedup vs baseline: 3.0468x; 1.1289x over previous
//
#include <hip/hip_runtime.h>

// ---------- constants ----------
#define B_   64
#define P_   196
#define ENC_ 512
#define ATT_ 256
#define DEC_ 256
#define EMB_ 256
#define V_   10000
#define T_   44
#define G4_  1024          // 4*DEC
#define XW_  768           // EMB+ENC (W_ih inner dim)
#define A1N_ 26624         // att1h per-b u32 count: 128 a2 * 208 p

using short8 = __attribute__((ext_vector_type(8))) short;
using f32x4  = __attribute__((ext_vector_type(4))) float;
typedef _Float16 f16x2 __attribute__((ext_vector_type(2)));

__device__ __forceinline__ unsigned short f2bf(float f) {
    unsigned int u = __float_as_uint(f);
    unsigned int r = (u + 0x7fffu + ((u >> 16) & 1u)) >> 16;
    return (unsigned short)r;
}

__device__ __forceinline__ unsigned int pkh2(float a, float b) {
    f16x2 t; t.x = (_Float16)a; t.y = (_Float16)b;
    return __builtin_bit_cast(unsigned int, t);
}

// fp16x2 dot with fp32 accumulate (single V_DOT2_F32_F16 where available)
__device__ __forceinline__ float fdot2f(float wbits, f16x2 xv, float acc) {
    f16x2 wv = __builtin_bit_cast(f16x2, wbits);
#if __has_builtin(__builtin_amdgcn_fdot2)
    return __builtin_amdgcn_fdot2(wv, xv, acc, false);
#else
    acc = fmaf((float)wv.x, (float)xv.x, acc);
    acc = fmaf((float)wv.y, (float)xv.y, acc);
    return acc;
#endif
}
__device__ __forceinline__ float fdot2u(unsigned int wbits, f16x2 xv, float acc) {
    f16x2 wv = __builtin_bit_cast(f16x2, wbits);
#if __has_builtin(__builtin_amdgcn_fdot2)
    return __builtin_amdgcn_fdot2(wv, xv, acc, false);
#else
    acc = fmaf((float)wv.x, (float)xv.x, acc);
    acc = fmaf((float)wv.y, (float)xv.y, acc);
    return acc;
#endif
}

// raw barrier: drains LDS ops only; global loads stay in flight (T4).
// All inter-thread communication in k_recur goes through LDS (lgkmcnt-tracked).
__device__ __forceinline__ void bar() {
    asm volatile("s_waitcnt lgkmcnt(0)" ::: "memory");
    __builtin_amdgcn_s_barrier();
    asm volatile("" ::: "memory");
}

// ---------- generic 32x32 transpose: dst[k*N + n] = src[n*stride + off + k] ----------
__global__ void k_transpose(const float* __restrict__ src, float* __restrict__ dst,
                            int N, int stride, int off) {
    __shared__ float t[32][33];
    int k0 = blockIdx.x * 32, n0 = blockIdx.y * 32;
    int tx = threadIdx.x & 31, ty = threadIdx.x >> 5;
    for (int r = ty; r < 32; r += 8)
        t[r][tx] = src[(size_t)(n0 + r) * stride + off + k0 + tx];
    __syncthreads();
    for (int r = ty; r < 32; r += 8)
        dst[(size_t)(k0 + r) * N + n0 + tx] = t[tx][r];
}

// ---------- pack W_dec_att [a][d] -> WdaP4[d4*256+a] = {W[a][4d4..4d4+3]} ----------
__global__ __launch_bounds__(256) void k_packWda(const float* __restrict__ Wda,
                                                 float4* __restrict__ WdaP4) {
    int d4 = blockIdx.x, a = threadIdx.x;
    float4 v;
    v.x = Wda[(size_t)a * DEC_ + 4 * d4 + 0];
    v.y = Wda[(size_t)a * DEC_ + 4 * d4 + 1];
    v.z = Wda[(size_t)a * DEC_ + 4 * d4 + 2];
    v.w = Wda[(size_t)a * DEC_ + 4 * d4 + 3];
    WdaP4[(size_t)d4 * 256 + a] = v;
}

// ---------- pack gate weights fp16: Wg4[k2*256+d] = 4 gates x half2(k=2k2,2k2+1) ----------
// k<512 -> W_ih[:, k] (ctx part); k>=512 -> W_hh[:, k-512] (h part). grid 384 x 256.
__global__ __launch_bounds__(256) void k_packWg(const float* __restrict__ Wih,
        const float* __restrict__ Whh, float4* __restrict__ Wg4) {
    int k2 = blockIdx.x, d = threadIdx.x;
    int k = 2 * k2;
    unsigned int o[4];
#pragma unroll
    for (int g = 0; g < 4; ++g) {
        int row = g * 256 + d;
        float a0, a1;
        if (k < ENC_) {
            a0 = Wih[(size_t)row * XW_ + k];
            a1 = Wih[(size_t)row * XW_ + k + 1];
        } else {
            a0 = Whh[(size_t)row * DEC_ + k - ENC_];
            a1 = Whh[(size_t)row * DEC_ + k - ENC_ + 1];
        }
        o[g] = pkh2(a0, a1);
    }
    float4 v;
    v.x = __builtin_bit_cast(float, o[0]);
    v.y = __builtin_bit_cast(float, o[1]);
    v.z = __builtin_bit_cast(float, o[2]);
    v.w = __builtin_bit_cast(float, o[3]);
    Wg4[(size_t)k2 * 256 + d] = v;
}

// ---------- pack enc fp16: encPh[(b*49+p4)*512+e] = uint2{h2(p=4p4,4p4+1), h2(4p4+2,4p4+3)} ----------
// grid: (64 b, 7), each y handles 7 p4 values
__global__ __launch_bounds__(256) void k_packenc(const float* __restrict__ enc,
                                                 uint2* __restrict__ encPh) {
    int b = blockIdx.x, p4b = blockIdx.y * 7;
    for (int p4 = p4b; p4 < p4b + 7; ++p4) {
        for (int e = threadIdx.x; e < ENC_; e += 256) {
            float a0 = enc[((size_t)b * P_ + 4 * p4 + 0) * ENC_ + e];
            float a1 = enc[((size_t)b * P_ + 4 * p4 + 1) * ENC_ + e];
            float a2 = enc[((size_t)b * P_ + 4 * p4 + 2) * ENC_ + e];
            float a3 = enc[((size_t)b * P_ + 4 * p4 + 3) * ENC_ + e];
            uint2 v; v.x = pkh2(a0, a1); v.y = pkh2(a2, a3);
            encPh[((size_t)b * 49 + p4) * ENC_ + e] = v;
        }
    }
}

// ---------- fp32 -> bf16 convert ----------
__global__ void k_cvt(const float* __restrict__ src, unsigned short* __restrict__ dst, int n) {
    int i = blockIdx.x * 256 + threadIdx.x;
    if (i < n) dst[i] = f2bf(src[i]);
}

// ---------- h0/c0 from mean-pooled encoder ----------
__global__ __launch_bounds__(256) void k_init_state(
        const float* __restrict__ enc,
        const float* __restrict__ W_init_h, const float* __restrict__ b_init_h,
        const float* __restrict__ W_init_c, const float* __restrict__ b_init_c,
        float* __restrict__ h0, float* __restrict__ c0) {
    int b = blockIdx.x, tid = threadIdx.x;
    __shared__ float avg[ENC_];
    for (int e = tid; e < ENC_; e += 256) {
        float s = 0.f;
        const float* p = enc + (size_t)b * P_ * ENC_ + e;
        for (int i = 0; i < P_; i++) s += p[(size_t)i * ENC_];
        avg[e] = s * (1.0f / (float)P_);
    }
    __syncthreads();
    int d = tid;  // 256 threads == DEC_
    float hs = b_init_h[d], cs = b_init_c[d];
    const float* wh = W_init_h + (size_t)d * ENC_;
    const float* wc = W_init_c + (size_t)d * ENC_;
    for (int e = 0; e < ENC_; e++) { float a = avg[e]; hs += a * wh[e]; cs += a * wc[e]; }
    h0[b * DEC_ + d] = hs;
    c0[b * DEC_ + d] = cs;
}

// ---------- att1h[b][a2(128)][208 p] = f16x2{ att1[2a2][p], att1[2a2+1][p] } ----------
// grid: 64 b * 4 a-tiles(64)
__global__ __launch_bounds__(256) void k_att1(
        const float* __restrict__ enc, const float* __restrict__ Wea,
        unsigned int* __restrict__ att1h) {
    int b = blockIdx.x >> 2, a0 = (blockIdx.x & 3) * 64;
    __shared__ float encT[32][257];   // [e_local][p] padded
    __shared__ float Wt[64][32];      // [a_local][e_local]
    int tid = threadIdx.x;
    int pl = tid & 63, ia = tid >> 6;
    float acc[16][4];
#pragma unroll
    for (int k = 0; k < 16; k++)
#pragma unroll
        for (int qq = 0; qq < 4; qq++) acc[k][qq] = 0.f;

    for (int e0 = 0; e0 < ENC_; e0 += 32) {
        {
            int j = tid & 31, pr = tid >> 5;
            for (int pass = 0; pass < 32; pass++) {
                int p = pr + pass * 8;
                float v = 0.f;
                if (p < P_) v = enc[((size_t)b * P_ + p) * ENC_ + e0 + j];
                encT[j][p] = v;
            }
            int r = tid >> 2, c0 = (tid & 3) * 8;
#pragma unroll
            for (int i = 0; i < 8; i++)
                Wt[r][c0 + i] = Wea[(size_t)(a0 + r) * ENC_ + e0 + c0 + i];
        }
        __syncthreads();
        for (int e = 0; e < 32; e++) {
            float e0v = encT[e][pl], e1v = encT[e][pl + 64];
            float e2v = encT[e][pl + 128], e3v = encT[e][pl + 192];
#pragma unroll
            for (int k = 0; k < 16; k++) {
                float w = Wt[ia * 16 + k][e];
                acc[k][0] += w * e0v; acc[k][1] += w * e1v;
                acc[k][2] += w * e2v; acc[k][3] += w * e3v;
            }
        }
        __syncthreads();
    }
#pragma unroll
    for (int k = 0; k < 16; k += 2)
#pragma unroll
        for (int qq = 0; qq < 4; qq++) {
            int p = pl + 64 * qq;
            int a = a0 + ia * 16 + k;
            if (p < P_)
                att1h[(size_t)b * A1N_ + (size_t)(a >> 1) * 208 + p] =
                    pkh2(acc[k][qq], acc[k + 1][qq]);
        }
}

// ---------- embW[(t*64+b)][j] = b_ih[j]+b_hh[j] + sum_e emb[cap(b,t)][e]*W_ih[j][512+e] ----------
__global__ __launch_bounds__(256) void k_embW(
        const int* __restrict__ caption, const float* __restrict__ embedding,
        const float* __restrict__ WiheT, const float* __restrict__ b_ih,
        const float* __restrict__ b_hh, float* __restrict__ embW) {
    int r0 = blockIdx.x * 16, tid = threadIdx.x;
    __shared__ float embL[16][256];
    __shared__ int capL[16];
    if (tid < 16) {
        int r = r0 + tid, t = r >> 6, b = r & 63;
        capL[tid] = caption[b * T_ + t];
    }
    __syncthreads();
#pragma unroll
    for (int lr = 0; lr < 16; lr++)
        embL[lr][tid] = embedding[(size_t)capL[lr] * EMB_ + tid];
    __syncthreads();
    float base0 = b_ih[tid] + b_hh[tid];
    float base1 = b_ih[tid + 256] + b_hh[tid + 256];
    float base2 = b_ih[tid + 512] + b_hh[tid + 512];
    float base3 = b_ih[tid + 768] + b_hh[tid + 768];
    float acc[16][4];
#pragma unroll
    for (int lr = 0; lr < 16; lr++) {
        acc[lr][0] = base0; acc[lr][1] = base1; acc[lr][2] = base2; acc[lr][3] = base3;
    }
    for (int e = 0; e < EMB_; e++) {
        const float* wr = WiheT + (size_t)e * G4_ + tid;
        float w0 = wr[0], w1 = wr[256], w2 = wr[512], w3 = wr[768];
#pragma unroll
        for (int lr = 0; lr < 16; lr++) {
            float ev = embL[lr][e];
            acc[lr][0] += w0 * ev; acc[lr][1] += w1 * ev;
            acc[lr][2] += w2 * ev; acc[lr][3] += w3 * ev;
        }
    }
#pragma unroll
    for (int lr = 0; lr < 16; lr++) {
        float* o = embW + (size_t)(r0 + lr) * G4_ + tid;
        o[0] = acc[lr][0]; o[256] = acc[lr][1]; o[512] = acc[lr][2]; o[768] = acc[lr][3];
    }
}

// ---------- the sequential recurrence: one block (1024 thr = 16 waves, 4 waves/EU) per b ----------
// att1 is fp16 LDS-resident (loaded once); per-XCD L2 set (Wg4+WdaP+encPh) now < 4 MB.
__global__ __launch_bounds__(1024, 4) void k_recur(
        const unsigned int* __restrict__ att1h, const float4* __restrict__ WdaP4,
        const float* __restrict__ W_full, const float4* __restrict__ Wg4,
        const float* __restrict__ embW, const uint2* __restrict__ encPh,
        const float* __restrict__ h0, const float* __restrict__ c0,
        unsigned short* __restrict__ Hbf, float* __restrict__ out_alpha) {
    int b = blockIdx.x, tid = threadIdx.x;
    int q = tid >> 8;        // 0..3 k-split group
    int r = tid & 255;
    int e5 = tid & 511, ph = tid >> 9;

    __shared__ __align__(16) float h_l[DEC_];
    __shared__ __align__(16) float att2_l[ATT_];
    __shared__ __align__(16) float wf_l[ATT_];
    __shared__ __align__(16) _Float16 xh[XW_];     // [ctx fp16(512); h fp16(256)]
    __shared__ float p1[4][256];
    __shared__ float p2[4][256];
    __shared__ float p3[2][512];
    __shared__ __align__(16) float4 p4s[4][256];
    __shared__ float red_l[4];
    __shared__ __align__(8) _Float16 alpha_h[208];
    // att1 fp16, resident for the whole kernel. +48 pad: P2 reads index up to 127*208+255.
    __shared__ unsigned int att1_lds[A1N_ + 48];

    // ---- stage att1 into LDS (once) + init state
    {
        const unsigned int* a1g = att1h + (size_t)b * A1N_;
        for (int i = tid; i < A1N_; i += 1024) att1_lds[i] = a1g[i];
    }
    if (tid < 256) {
        float hv = h0[b * DEC_ + tid];
        h_l[tid] = hv;
        xh[512 + tid] = (_Float16)hv;
        wf_l[tid] = W_full[tid];
    }
    float c = (tid < 256) ? c0[b * DEC_ + tid] : 0.f;
    __syncthreads();

    const uint2* encb = encPh + (size_t)b * (49 * ENC_);

    for (int t = 0; t < T_; ++t) {
        // ---- P1: att2 partial over d in [q*64,(q+1)*64), thread r = a (fp32)
        float a2 = 0.f;
#pragma unroll 4
        for (int i = 0; i < 16; i++) {
            int d4 = q * 16 + i;
            float4 w = WdaP4[(size_t)d4 * 256 + r];
            float4 h4 = *reinterpret_cast<const float4*>(&h_l[4 * d4]);
            a2 += w.x * h4.x + w.y * h4.y + w.z * h4.z + w.w * h4.w;
        }
        p1[q][r] = a2;
        bar();
        if (tid < 256) att2_l[tid] = p1[0][tid] + p1[1][tid] + p1[2][tid] + p1[3][tid];
        bar();

        // ---- P2: score partial over a-pairs in [q*32,(q+1)*32), thread r = p (LDS att1 fp16)
        float sp = 0.f;
#pragma unroll 4
        for (int i = 0; i < 32; i++) {
            int a2i = q * 32 + i;
            f16x2 av = __builtin_bit_cast(f16x2, att1_lds[a2i * 208 + r]);
            float2 t2 = *reinterpret_cast<const float2*>(&att2_l[2 * a2i]);
            float2 w4 = *reinterpret_cast<const float2*>(&wf_l[2 * a2i]);
            sp += fmaxf((float)av.x + t2.x, 0.f) * w4.x +
                  fmaxf((float)av.y + t2.y, 0.f) * w4.y;
        }
        p2[q][r] = sp;
        bar();

        // ---- softmax (no max-subtraction; fp32 exp safe for these score magnitudes)
        float ex = 0.f;
        if (tid < 256) {
            float s = p2[0][tid] + p2[1][tid] + p2[2][tid] + p2[3][tid];
            ex = (tid < P_) ? __expf(s) : 0.f;
            float sm = ex;
#pragma unroll
            for (int off = 32; off; off >>= 1) sm += __shfl_xor(sm, off);
            if ((tid & 63) == 0) red_l[tid >> 6] = sm;
        }
        bar();
        if (tid < 256) {
            float sm = red_l[0] + red_l[1] + red_l[2] + red_l[3];
            float alpha = ex / sm;           // == 0 for tid >= P_
            if (tid < 208) alpha_h[tid] = (_Float16)alpha;
            if (tid < P_) out_alpha[(size_t)b * (T_ * P_) + t * P_ + tid] = alpha;
        }
        bar();

        // ---- P3: ctx partial, thread e = e5, p4 split 2-way (fp16 enc, fdot2)
        float cx = 0.f;
        {
            int p4b = ph ? 25 : 0, p4e = ph ? 49 : 25;
#pragma unroll 5
            for (int p4 = p4b; p4 < p4e; p4++) {
                uint2 ev = encb[(size_t)p4 * ENC_ + e5];
                f16x2 a01 = *reinterpret_cast<const f16x2*>(&alpha_h[4 * p4]);
                f16x2 a23 = *reinterpret_cast<const f16x2*>(&alpha_h[4 * p4 + 2]);
                cx = fdot2u(ev.x, a01, cx);
                cx = fdot2u(ev.y, a23, cx);
            }
        }
        p3[ph][e5] = cx;
        // embW row prefetch (used in P5; 4 VGPRs held across P4)
        float ew0 = 0.f, ew1 = 0.f, ew2 = 0.f, ew3 = 0.f;
        if (tid < 256) {
            const float* ew = embW + ((size_t)t * B_ + b) * G4_;
            ew0 = ew[tid]; ew1 = ew[tid + 256]; ew2 = ew[tid + 512]; ew3 = ew[tid + 768];
        }
        bar();
        if (tid < 512) xh[tid] = (_Float16)(p3[0][tid] + p3[1][tid]);
        bar();

        // ---- P4: gates, k2 in [q*96,(q+1)*96), fp16 weights, thread r = d (fdot2)
        float4 acc = {0.f, 0.f, 0.f, 0.f};
#pragma unroll 8
        for (int i = 0; i < 96; i++) {
            int k2 = q * 96 + i;
            float4 w = Wg4[(size_t)k2 * 256 + r];
            f16x2 xv = *reinterpret_cast<const f16x2*>(&xh[2 * k2]);
            acc.x = fdot2f(w.x, xv, acc.x);
            acc.y = fdot2f(w.y, xv, acc.y);
            acc.z = fdot2f(w.z, xv, acc.z);
            acc.w = fdot2f(w.w, xv, acc.w);
        }
        p4s[q][r] = acc;
        bar();

        // ---- P5: reduce partials + LSTM pointwise (torch gate order i,f,g,o)
        if (tid < 256) {
            float4 g0 = p4s[0][tid], g1 = p4s[1][tid], g2 = p4s[2][tid], g3 = p4s[3][tid];
            float gi = g0.x + g1.x + g2.x + g3.x + ew0;
            float gf = g0.y + g1.y + g2.y + g3.y + ew1;
            float gg = g0.z + g1.z + g2.z + g3.z + ew2;
            float go = g0.w + g1.w + g2.w + g3.w + ew3;
            float i_g = 1.f / (1.f + __expf(-gi));
            float f_g = 1.f / (1.f + __expf(-gf));
            float g_g = tanhf(gg);
            float o_g = 1.f / (1.f + __expf(-go));
            c = f_g * c + i_g * g_g;
            float hn = o_g * tanhf(c);
            h_l[tid] = hn;
            xh[512 + tid] = (_Float16)hn;
            Hbf[((size_t)t * B_ + b) * DEC_ + tid] = f2bf(hn);
        }
        bar();
    }
}

// ---------- logits: C[m][n] = H[m,:] . Wout[n,:] + b_out[n], bf16 MFMA ----------
__global__ __launch_bounds__(256) void k_logits(
        const unsigned short* __restrict__ Hbf, const unsigned short* __restrict__ Woutbf,
        const float* __restrict__ b_out, float* __restrict__ out) {
    int n0 = blockIdx.x * 128, m0 = blockIdx.y * 128;
    __shared__ __align__(16) unsigned short At[128][40];
    __shared__ __align__(16) unsigned short Bt[128][40];
    int tid = threadIdx.x;
    int lane = tid & 63, w = tid >> 6;
    int wm = (w & 1) * 64, wn = (w >> 1) * 64;
    f32x4 acc[4][4];
#pragma unroll
    for (int i = 0; i < 4; i++)
#pragma unroll
        for (int j = 0; j < 4; j++) acc[i][j] = (f32x4){0.f, 0.f, 0.f, 0.f};

    for (int k0 = 0; k0 < DEC_; k0 += 32) {
#pragma unroll
        for (int l = 0; l < 2; l++) {
            int idx = l * 256 + tid;         // 0..511
            int r = idx >> 2, kc = (idx & 3) * 8;
            uint4 av = *reinterpret_cast<const uint4*>(&Hbf[(size_t)(m0 + r) * DEC_ + k0 + kc]);
            *reinterpret_cast<uint4*>(&At[r][kc]) = av;
            uint4 bv = make_uint4(0u, 0u, 0u, 0u);
            if (n0 + r < V_)
                bv = *reinterpret_cast<const uint4*>(&Woutbf[(size_t)(n0 + r) * DEC_ + k0 + kc]);
            *reinterpret_cast<uint4*>(&Bt[r][kc]) = bv;
        }
        __syncthreads();
        int qk = (lane >> 4) * 8, fr = lane & 15;
        short8 a[4], bb[4];
#pragma unroll
        for (int i = 0; i < 4; i++) {
            a[i]  = *reinterpret_cast<const short8*>(&At[wm + i * 16 + fr][qk]);
            bb[i] = *reinterpret_cast<const short8*>(&Bt[wn + i * 16 + fr][qk]);
        }
#pragma unroll
        for (int i = 0; i < 4; i++)
#pragma unroll
            for (int j = 0; j < 4; j++)
                acc[i][j] = __builtin_amdgcn_mfma_f32_16x16x32_bf16(a[i], bb[j], acc[i][j], 0, 0, 0);
        __syncthreads();
    }
    int col = lane & 15, qr = (lane >> 4) * 4;
#pragma unroll
    for (int j = 0; j < 4; j++) {
        int n = n0 + wn + j * 16 + col;
        if (n < V_) {
            float bo = b_out[n];
#pragma unroll
            for (int i = 0; i < 4; i++)
#pragma unroll
                for (int rr = 0; rr < 4; rr++) {
                    int m = m0 + wm + i * 16 + qr + rr;
                    int t = m >> 6, bb2 = m & 63;
                    out[(size_t)bb2 * (T_ * V_) + (size_t)t * V_ + n] = acc[i][j][rr] + bo;
                }
        }
    }
}

// ---------- launch ----------
extern "C" void kernel_launch(void* const* d_in, const int* in_sizes, int n_in,
                              void* d_out, int out_size, void* d_ws, size_t ws_size,
                              hipStream_t stream) {
    const float* enc       = (const float*)d_in[0];
    const int*   caption   = (const int*)d_in[1];
    const float* W_enc_att = (const float*)d_in[2];
    const float* W_dec_att = (const float*)d_in[3];
    const float* W_full    = (const float*)d_in[4];
    const float* embedding = (const float*)d_in[5];
    const float* W_init_h  = (const float*)d_in[6];
    const float* b_init_h  = (const float*)d_in[7];
    const float* W_init_c  = (const float*)d_in[8];
    const float* b_init_c  = (const float*)d_in[9];
    const float* W_ih      = (const float*)d_in[10];
    const float* b_ih      = (const float*)d_in[11];
    const float* W_hh      = (const float*)d_in[12];
    const float* b_hh      = (const float*)d_in[13];
    const float* W_out     = (const float*)d_in[14];
    const float* b_out     = (const float*)d_in[15];

    float* ws = (float*)d_ws;
    float* h0    = ws;                    //      16384
    float* c0    = ws + 16384;            //      16384
    float* WdaP  = ws + 32768;            //      65536  [64 d4][256 a] float4
    float* WiheT = ws + 98304;            //     262144  [256 e][1024 j]
    float* Wg4   = ws + 360448;           //     393216  [384 k2][256 d] 4x half2
    float* embW  = ws + 753664;           //    2883584  [t*64+b][1024]
    float* att1h = ws + 3637248;          //    1703936  [b][128 a2][208 p] f16x2 (u32)
    float* encPh = ws + 5341184;          //    3211264  [b][49 p4][512 e] uint2 fp16
    unsigned short* Hbf    = (unsigned short*)(ws + 8552448);   // 2816*256 bf16 = 360448 floats
    unsigned short* Woutbf = (unsigned short*)(ws + 8912896);   // 10000*256 bf16 = 1280000 floats
    // total: 8912896 + 1280000 = 10192896 floats ~= 40.8 MB

    float* out_pred  = (float*)d_out;
    float* out_alpha = out_pred + (size_t)B_ * T_ * V_;

    k_transpose<<<dim3(8, 32), 256, 0, stream>>>(W_ih, WiheT, G4_, XW_, ENC_);
    k_packWda<<<64, 256, 0, stream>>>(W_dec_att, (float4*)WdaP);
    k_packWg<<<384, 256, 0, stream>>>(W_ih, W_hh, (float4*)Wg4);
    k_packenc<<<dim3(64, 7), 256, 0, stream>>>(enc, (uint2*)encPh);
    k_cvt<<<10000, 256, 0, stream>>>(W_out, Woutbf, V_ * DEC_);
    k_init_state<<<B_, 256, 0, stream>>>(enc, W_init_h, b_init_h, W_init_c, b_init_c, h0, c0);
    k_att1<<<B_ * 4, 256, 0, stream>>>(enc, W_enc_att, (unsigned int*)att1h);
    k_embW<<<176, 256, 0, stream>>>(caption, embedding, WiheT, b_ih, b_hh, embW);
    k_recur<<<B_, 1024, 0, stream>>>((const unsigned int*)att1h, (const float4*)WdaP, W_full,
                                     (const float4*)Wg4, embW, (const uint2*)encPh,
                                     h0, c0, Hbf, out_alpha);
    k_logits<<<dim3(79, 22), 256, 0, stream>>>(Hbf, Woutbf, b_out, out_pred);
}